// Round 6
// baseline (665.032 us; speedup 1.0000x reference)
//
#include <hip/hip_runtime.h>
#include <math.h>

#define B_ 4
#define S_ 2048
#define H_ 16
#define D_ 64
#define C_ 128          // prefix-state chunk (kvbuf granularity, 16.8 MB in d_ws)
#define NC_ (S_ / C_)   // 16 chunks per sequence
#define BH_ (B_ * H_)   // 64 sequences
#define SPLIT_ 4
#define T_ 64           // out-tile rows per wave
#define NT_ (S_ / T_)   // 32 tiles per sequence

// ---------------------------------------------------------------------------
// Kernel 1 (register style): per-chunk KV outer-product sums, one wave per
// chunk. lane <-> dk. K[s][lane] is a coalesced 256B load; V rows stream as
// wave-uniform float4 loads (1 cache line/inst). Zero LDS, zero barriers.
// grid = 256 blocks x 256 thr (4 waves = 4 chunks per block), 1024 chunks.
// ---------------------------------------------------------------------------
__global__ __launch_bounds__(256) void kv_chunk_kernel(
    const float* __restrict__ qk, const float* __restrict__ v,
    float* __restrict__ kvbuf)
{
  const int wid = blockIdx.x * 4 + (threadIdx.x >> 6);  // chunk id 0..1023
  const int lane = threadIdx.x & 63;                    // dk
  const int bh = wid >> 4, c = wid & 15;
  const int b = bh >> 4, h = bh & 15;
  const int t0 = c * C_;

  const float* kp = qk + ((((size_t)(b * S_ + t0)) * 2 + 1) * H_ + h) * D_;
  const float* vp = v + (((size_t)(b * S_ + t0)) * H_ + h) * D_;

  float acc[D_];
  #pragma unroll
  for (int i = 0; i < D_; ++i) acc[i] = 0.f;

  #pragma unroll 2
  for (int s = 0; s < C_; ++s) {
    const float* kr = kp + (size_t)s * (2 * H_ * D_);
    const float* vr = vp + (size_t)s * (H_ * D_);
    float kv_ = kr[lane];                       // coalesced per-lane
    #pragma unroll
    for (int jc = 0; jc < 4; ++jc) {            // 16 dv per sub-chunk
      float4 a0 = *reinterpret_cast<const float4*>(vr + jc * 16 + 0);
      float4 a1 = *reinterpret_cast<const float4*>(vr + jc * 16 + 4);
      float4 a2 = *reinterpret_cast<const float4*>(vr + jc * 16 + 8);
      float4 a3 = *reinterpret_cast<const float4*>(vr + jc * 16 + 12);
      acc[jc*16+ 0] += kv_ * a0.x; acc[jc*16+ 1] += kv_ * a0.y;
      acc[jc*16+ 2] += kv_ * a0.z; acc[jc*16+ 3] += kv_ * a0.w;
      acc[jc*16+ 4] += kv_ * a1.x; acc[jc*16+ 5] += kv_ * a1.y;
      acc[jc*16+ 6] += kv_ * a1.z; acc[jc*16+ 7] += kv_ * a1.w;
      acc[jc*16+ 8] += kv_ * a2.x; acc[jc*16+ 9] += kv_ * a2.y;
      acc[jc*16+10] += kv_ * a2.z; acc[jc*16+11] += kv_ * a2.w;
      acc[jc*16+12] += kv_ * a3.x; acc[jc*16+13] += kv_ * a3.y;
      acc[jc*16+14] += kv_ * a3.z; acc[jc*16+15] += kv_ * a3.w;
    }
  }

  // store M[dk=lane][dv], row-major per (bh,chunk) — layout unchanged
  float* op = kvbuf + (size_t)wid * (D_ * D_) + (size_t)lane * D_;
  #pragma unroll
  for (int j = 0; j < 16; ++j) {
    *reinterpret_cast<float4*>(op + 4 * j) =
        make_float4(acc[4*j], acc[4*j+1], acc[4*j+2], acc[4*j+3]);
  }
}

// ---------------------------------------------------------------------------
// Kernel 2: in-place EXCLUSIVE prefix sum of the D*D states over chunks.
// UNCHANGED (measured tiny).
// ---------------------------------------------------------------------------
__global__ __launch_bounds__(256) void prefix_kernel(float* __restrict__ kvbuf)
{
  const int bid = blockIdx.x;
  const int bh = bid / SPLIT_, part = bid % SPLIT_;
  const size_t off = (size_t)part * 1024 + (size_t)threadIdx.x * 4;
  float4 run = make_float4(0.f, 0.f, 0.f, 0.f);
  for (int c = 0; c < NC_; ++c) {
    float* p = kvbuf + ((size_t)bh * NC_ + c) * (D_ * D_) + off;
    float4 t = *reinterpret_cast<float4*>(p);
    *reinterpret_cast<float4*>(p) = run;               // exclusive prefix
    run.x += t.x; run.y += t.y; run.z += t.z; run.w += t.w;
  }
}

// ---------------------------------------------------------------------------
// Kernel 3 (register style): one wave per 64-row output tile, lane <-> t-row.
// Q row (64 f32) and out (64 f32) in VGPRs. M rows / K rows / V rows stream
// as wave-uniform loads. Zero LDS, zero barriers, no score redistribution.
// grid = 512 blocks x 256 thr (4 indep waves), 2048 tiles.
// ---------------------------------------------------------------------------
__global__ __launch_bounds__(256) void out_kernel(
    const float* __restrict__ qk, const float* __restrict__ v,
    const float* __restrict__ nrm, const float* __restrict__ kvbuf,
    float* __restrict__ outp)
{
  const int wid = blockIdx.x * 4 + (threadIdx.x >> 6);  // tile id 0..2047
  const int lane = threadIdx.x & 63;
  const int bh = wid >> 5;          // NT_=32 tiles per sequence
  const int tt = wid & 31;
  const int b = bh >> 4, h = bh & 15;
  const int t0 = tt * T_;
  const int c = tt >> 1;            // chunk (C_=128) this tile belongs to
  const int t = t0 + lane;          // this lane's global row

  const float* qrow = qk + ((((size_t)(b * S_ + t)) * 2 + 0) * H_ + h) * D_;

  // Q row into registers (static indices only — never runtime-indexed)
  float q[D_];
  #pragma unroll
  for (int j = 0; j < 16; ++j) {
    float4 x = *reinterpret_cast<const float4*>(qrow + 4 * j);
    q[4*j] = x.x; q[4*j+1] = x.y; q[4*j+2] = x.z; q[4*j+3] = x.w;
  }
  float o[D_];
  #pragma unroll
  for (int i = 0; i < D_; ++i) o[i] = 0.f;

  // ---- phase A: cross-chunk  o += q · M_prefix  (rank-64, M wave-uniform)
  if (c > 0) {
    const float* M = kvbuf + ((size_t)bh * NC_ + c) * (D_ * D_);
    for (int kq = 0; kq < 16; ++kq) {
      // reload q quad from L1 (keeps q-index static w/o 64x full unroll)
      float4 q4 = *reinterpret_cast<const float4*>(qrow + 4 * kq);
      const float* mr = M + (size_t)kq * 4 * D_;
      #pragma unroll
      for (int i = 0; i < 4; ++i) {
        float qv = (i == 0) ? q4.x : (i == 1) ? q4.y : (i == 2) ? q4.z : q4.w;
        const float* mri = mr + i * D_;
        #pragma unroll
        for (int j = 0; j < 16; ++j) {
          float4 m4 = *reinterpret_cast<const float4*>(mri + 4 * j);
          o[4*j]   += qv * m4.x;
          o[4*j+1] += qv * m4.y;
          o[4*j+2] += qv * m4.z;
          o[4*j+3] += qv * m4.w;
        }
      }
    }
  }

  // ---- phase B: rows s in [c*128, t0+64): dense part + causal part
  const int s_lo = c * C_;
  const int s_hi = t0 + T_;
  const float* kbase2 = qk + ((((size_t)b * S_) * 2 + 1) * H_ + h) * D_;
  const float* vbase2 = v + (((size_t)b * S_) * H_ + h) * D_;

  #pragma unroll 2
  for (int s = s_lo; s < s_hi; ++s) {
    const float* kr = kbase2 + (size_t)s * (2 * H_ * D_);   // wave-uniform
    float p0 = 0.f, p1 = 0.f, p2 = 0.f, p3 = 0.f;
    #pragma unroll
    for (int j = 0; j < 16; ++j) {
      float4 k4 = *reinterpret_cast<const float4*>(kr + 4 * j);
      p0 += q[4*j]   * k4.x;
      p1 += q[4*j+1] * k4.y;
      p2 += q[4*j+2] * k4.z;
      p3 += q[4*j+3] * k4.w;
    }
    float sc = (p0 + p1) + (p2 + p3);
    sc = (s <= t) ? sc : 0.f;                 // causal (incl. diagonal)
    const float* vr = vbase2 + (size_t)s * (H_ * D_);       // wave-uniform
    #pragma unroll
    for (int j = 0; j < 16; ++j) {
      float4 v4 = *reinterpret_cast<const float4*>(vr + 4 * j);
      o[4*j]   += sc * v4.x;
      o[4*j+1] += sc * v4.y;
      o[4*j+2] += sc * v4.z;
      o[4*j+3] += sc * v4.w;
    }
  }

  // ---- epilogue: scale by exp(-n) and store
  float nv = nrm[((size_t)(b * S_ + t)) * H_ + h];
  float inv = expf(-nv);
  float* op = outp + (((size_t)(b * S_ + t)) * H_ + h) * D_;
  #pragma unroll
  for (int j = 0; j < 16; ++j) {
    *reinterpret_cast<float4*>(op + 4 * j) =
        make_float4(o[4*j]*inv, o[4*j+1]*inv, o[4*j+2]*inv, o[4*j+3]*inv);
  }
}

extern "C" void kernel_launch(void* const* d_in, const int* in_sizes, int n_in,
                              void* d_out, int out_size, void* d_ws, size_t ws_size,
                              hipStream_t stream) {
  const float* qk  = (const float*)d_in[0];   // (B,S,2,H,D) f32
  const float* v   = (const float*)d_in[1];   // (B,S,H,D)   f32
  const float* nrm = (const float*)d_in[2];   // (B,S,H)     f32
  float* out = (float*)d_out;                 // (B,S,H,D)   f32
  float* kvbuf = (float*)d_ws;                // BH_*NC_*D*D floats = 16.8 MB

  kv_chunk_kernel<<<dim3(BH_ * NC_ / 4), dim3(256), 0, stream>>>(qk, v, kvbuf);
  prefix_kernel<<<dim3(BH_ * SPLIT_), dim3(256), 0, stream>>>(kvbuf);
  out_kernel<<<dim3(BH_ * NT_ / 4), dim3(256), 0, stream>>>(qk, v, nrm, kvbuf, out);
}

// Round 7
// 207.871 us; speedup vs baseline: 3.1993x; 3.1993x over previous
//
#include <hip/hip_runtime.h>
#include <math.h>

#define B_ 4
#define S_ 2048
#define H_ 16
#define D_ 64
#define C_ 128
#define NC_ (S_ / C_)   // 16 chunks per sequence
#define BH_ (B_ * H_)   // 64 sequences
#define SPLIT_ 4

// ---------------------------------------------------------------------------
// Kernel 1: per-chunk KV outer-product sums (round-5 version, verbatim).
// ---------------------------------------------------------------------------
__global__ __launch_bounds__(256) void kv_chunk_kernel(
    const float* __restrict__ qk, const float* __restrict__ v,
    float* __restrict__ kvbuf)
{
  __shared__ float Kl[C_][D_];   // 32 KB
  __shared__ float Vl[C_][D_];   // 32 KB
  const int bid = blockIdx.x;
  const int bh = bid / NC_, c = bid % NC_;
  const int b = bh / H_, h = bh % H_;
  const int t0 = c * C_;
  const int tid = threadIdx.x;

  const size_t kbase = (((size_t)b * S_ * 2 + 1) * H_ + h) * D_;
  const size_t vbase = (((size_t)b * S_) * H_ + h) * D_;

  #pragma unroll
  for (int i = 0; i < 8; ++i) {
    int f = tid + i * 256;
    int row = f >> 4, c4 = (f & 15) << 2;
    size_t t = (size_t)t0 + row;
    *reinterpret_cast<float4*>(&Kl[row][c4]) =
        *reinterpret_cast<const float4*>(qk + kbase + t * (2 * H_ * D_) + c4);
    *reinterpret_cast<float4*>(&Vl[row][c4]) =
        *reinterpret_cast<const float4*>(v + vbase + t * (H_ * D_) + c4);
  }
  __syncthreads();

  const int dkt = tid >> 4;
  const int dvt = tid & 15;
  float acc[4][4] = {};
  #pragma unroll 4
  for (int s = 0; s < C_; ++s) {
    float4 k4 = *reinterpret_cast<const float4*>(&Kl[s][dkt * 4]);
    float4 v4 = *reinterpret_cast<const float4*>(&Vl[s][dvt * 4]);
    float kk[4] = {k4.x, k4.y, k4.z, k4.w};
    float vv[4] = {v4.x, v4.y, v4.z, v4.w};
    #pragma unroll
    for (int a = 0; a < 4; ++a)
      #pragma unroll
      for (int e = 0; e < 4; ++e)
        acc[a][e] += kk[a] * vv[e];
  }
  float* outp = kvbuf + (size_t)bid * (D_ * D_);
  #pragma unroll
  for (int a = 0; a < 4; ++a) {
    float4 o = make_float4(acc[a][0], acc[a][1], acc[a][2], acc[a][3]);
    *reinterpret_cast<float4*>(outp + (dkt * 4 + a) * D_ + dvt * 4) = o;
  }
}

// ---------------------------------------------------------------------------
// Kernel 2: exclusive prefix over chunks (unchanged).
// ---------------------------------------------------------------------------
__global__ __launch_bounds__(256) void prefix_kernel(float* __restrict__ kvbuf)
{
  const int bid = blockIdx.x;
  const int bh = bid / SPLIT_, part = bid % SPLIT_;
  const size_t off = (size_t)part * 1024 + (size_t)threadIdx.x * 4;
  float4 run = make_float4(0.f, 0.f, 0.f, 0.f);
  for (int c = 0; c < NC_; ++c) {
    float* p = kvbuf + ((size_t)bh * NC_ + c) * (D_ * D_) + off;
    float4 t = *reinterpret_cast<float4*>(p);
    *reinterpret_cast<float4*>(p) = run;
    run.x += t.x; run.y += t.y; run.z += t.z; run.w += t.w;
  }
}

// ---------------------------------------------------------------------------
// Kernel 3 (rebalanced): thread = (TG=tid>>4 -> 8 t-rows, SG=tid&15 -> 4 cols).
// Score tile 8t x 4s over a 64-wide s-window (2 passes). Qt2 XOR-swizzled by
// tg; Sc XOR-swizzled by row-owner tg (conflict-free reads). M and V stream
// from global (L1/L2). LDS = 32+16+32 = 80 KB -> 2 blocks/CU.
// ---------------------------------------------------------------------------
__global__ __launch_bounds__(256) void out_kernel(
    const float* __restrict__ qk, const float* __restrict__ v,
    const float* __restrict__ nrm, const float* __restrict__ kvbuf,
    float* __restrict__ outp)
{
  __shared__ float Qt2[16][D_][8];   // 32 KB  [tg][d ^ (tg&7)][row-in-group]
  __shared__ float Kt[D_][64];       // 16 KB  [d][s-in-window]
  __shared__ float Sc[C_][64];       // 32 KB  [t][4*(sq ^ (t>>3 & 7)) + jj]

  const int bid = blockIdx.x;
  const int bh = bid / NC_, c = bid % NC_;
  const int b = bh / H_, h = bh % H_;
  const int t0 = c * C_;
  const int tid = threadIdx.x;
  const int TG = tid >> 4;          // 0..15  rows tb..tb+7
  const int SG = tid & 15;          // 0..15  score s-quad / dv-quad owner
  const int tb = TG * 8;
  const int key = TG & 7;

  // ---- stage Q into swizzled Qt2 ----
  {
    const int t = tid >> 1;                 // 0..127
    const int d0 = (tid & 1) * 32;
    const int wtg = t >> 3, wrow = t & 7, wkey = wtg & 7;
    const float* qrow =
        qk + ((((size_t)b * S_ + t0 + t) * 2 + 0) * H_ + h) * D_ + d0;
    float tmp[32];
    #pragma unroll
    for (int i = 0; i < 8; ++i) {
      float4 x = *reinterpret_cast<const float4*>(qrow + i * 4);
      tmp[i*4+0] = x.x; tmp[i*4+1] = x.y; tmp[i*4+2] = x.z; tmp[i*4+3] = x.w;
    }
    #pragma unroll
    for (int i = 0; i < 32; ++i)
      Qt2[wtg][(d0 + i) ^ wkey][wrow] = tmp[i];
  }
  __syncthreads();

  float o[8][4] = {};

  // ---- phase A: o += q . M_prefix  (M from global, wave-shared via cache) --
  if (c > 0) {
    const float* M = kvbuf + ((size_t)bh * NC_ + c) * (D_ * D_);
    #pragma unroll 4
    for (int dk = 0; dk < D_; ++dk) {
      const float* qp = &Qt2[TG][dk ^ key][0];
      float4 qa = *reinterpret_cast<const float4*>(qp);
      float4 qb = *reinterpret_cast<const float4*>(qp + 4);
      float4 m4 = *reinterpret_cast<const float4*>(M + dk * D_ + SG * 4);
      float qv[8] = {qa.x, qa.y, qa.z, qa.w, qb.x, qb.y, qb.z, qb.w};
      float mv[4] = {m4.x, m4.y, m4.z, m4.w};
      #pragma unroll
      for (int i = 0; i < 8; ++i)
        #pragma unroll
        for (int jj = 0; jj < 4; ++jj)
          o[i][jj] += qv[i] * mv[jj];
    }
  }

  // ---- phase B: two 64-wide s-windows ----
  const float* kbase2 = qk + ((((size_t)b * S_) * 2 + 1) * H_ + h) * D_;
  const float* vbase2 = v + (((size_t)b * S_) * H_ + h) * D_;

  for (int j = 0; j < 2; ++j) {
    if (j > 0) __syncthreads();   // Sc(j-1)/Kt(j-1) fully consumed
    { // stage Kt (transposed): 64 rows x 64 dims
      const int sl = tid >> 2;              // 0..63
      const int d0 = (tid & 3) * 16;
      const float* krow = kbase2 + (size_t)(t0 + j * 64 + sl) * (2 * H_ * D_) + d0;
      #pragma unroll
      for (int q4 = 0; q4 < 4; ++q4) {
        float4 kx = *reinterpret_cast<const float4*>(krow + q4 * 4);
        Kt[d0 + q4*4 + 0][sl] = kx.x;
        Kt[d0 + q4*4 + 1][sl] = kx.y;
        Kt[d0 + q4*4 + 2][sl] = kx.z;
        Kt[d0 + q4*4 + 3][sl] = kx.w;
      }
    }
    __syncthreads();

    const bool active = (tb >= j * 64);
    if (active) {
      float sc[8][4] = {};
      #pragma unroll 4
      for (int d = 0; d < D_; ++d) {
        const float* qp = &Qt2[TG][d ^ key][0];
        float4 qa = *reinterpret_cast<const float4*>(qp);
        float4 qb = *reinterpret_cast<const float4*>(qp + 4);
        float4 k4 = *reinterpret_cast<const float4*>(&Kt[d][SG * 4]);
        float qv[8] = {qa.x, qa.y, qa.z, qa.w, qb.x, qb.y, qb.z, qb.w};
        float kv[4] = {k4.x, k4.y, k4.z, k4.w};
        #pragma unroll
        for (int i = 0; i < 8; ++i)
          #pragma unroll
          for (int jj = 0; jj < 4; ++jj)
            sc[i][jj] += qv[i] * kv[jj];
      }
      // causal mask (inclusive diagonal, chunk-local indices) + swizzled store
      #pragma unroll
      for (int i = 0; i < 8; ++i) {
        const int tl = tb + i;
        float4 w;
        w.x = (j*64 + SG*4 + 0 <= tl) ? sc[i][0] : 0.f;
        w.y = (j*64 + SG*4 + 1 <= tl) ? sc[i][1] : 0.f;
        w.z = (j*64 + SG*4 + 2 <= tl) ? sc[i][2] : 0.f;
        w.w = (j*64 + SG*4 + 3 <= tl) ? sc[i][3] : 0.f;
        *reinterpret_cast<float4*>(&Sc[tl][4 * (SG ^ key)]) = w;
      }
    }
    __syncthreads();

    if (active) {
      #pragma unroll 2
      for (int sq = 0; sq < 16; ++sq) {
        const int sg0 = t0 + j * 64 + sq * 4;
        float4 v0 = *reinterpret_cast<const float4*>(vbase2 + (size_t)(sg0+0) * (H_*D_) + SG*4);
        float4 v1 = *reinterpret_cast<const float4*>(vbase2 + (size_t)(sg0+1) * (H_*D_) + SG*4);
        float4 v2 = *reinterpret_cast<const float4*>(vbase2 + (size_t)(sg0+2) * (H_*D_) + SG*4);
        float4 v3 = *reinterpret_cast<const float4*>(vbase2 + (size_t)(sg0+3) * (H_*D_) + SG*4);
        const int scol = 4 * (sq ^ key);
        #pragma unroll
        for (int i = 0; i < 8; ++i) {
          float4 s4 = *reinterpret_cast<const float4*>(&Sc[tb + i][scol]);
          o[i][0] += s4.x*v0.x + s4.y*v1.x + s4.z*v2.x + s4.w*v3.x;
          o[i][1] += s4.x*v0.y + s4.y*v1.y + s4.z*v2.y + s4.w*v3.y;
          o[i][2] += s4.x*v0.z + s4.y*v1.z + s4.z*v2.z + s4.w*v3.z;
          o[i][3] += s4.x*v0.w + s4.y*v1.w + s4.z*v2.w + s4.w*v3.w;
        }
      }
    }
  }

  // ---- epilogue ----
  #pragma unroll
  for (int i = 0; i < 8; ++i) {
    const size_t t = (size_t)t0 + tb + i;
    float nv = nrm[((size_t)b * S_ + t) * H_ + h];
    float inv = expf(-nv);
    float4 ov = make_float4(o[i][0]*inv, o[i][1]*inv, o[i][2]*inv, o[i][3]*inv);
    *reinterpret_cast<float4*>(
        outp + (((size_t)b * S_ + t) * H_ + h) * D_ + SG * 4) = ov;
  }
}

extern "C" void kernel_launch(void* const* d_in, const int* in_sizes, int n_in,
                              void* d_out, int out_size, void* d_ws, size_t ws_size,
                              hipStream_t stream) {
  const float* qk  = (const float*)d_in[0];   // (B,S,2,H,D) f32
  const float* v   = (const float*)d_in[1];   // (B,S,H,D)   f32
  const float* nrm = (const float*)d_in[2];   // (B,S,H)     f32
  float* out = (float*)d_out;                 // (B,S,H,D)   f32
  float* kvbuf = (float*)d_ws;                // 16.8 MB

  kv_chunk_kernel<<<dim3(BH_ * NC_), dim3(256), 0, stream>>>(qk, v, kvbuf);
  prefix_kernel<<<dim3(BH_ * SPLIT_), dim3(256), 0, stream>>>(kvbuf);
  out_kernel<<<dim3(BH_ * NC_), dim3(256), 0, stream>>>(qk, v, nrm, kvbuf, out);
}